// Round 3
// baseline (220.757 us; speedup 1.0000x reference)
//
#include <hip/hip_runtime.h>

#define N_NODES 50000
#define N_EDGES 800000
#define CAP 64               // per-node bucket capacity (Poisson(16): P(>64)~1e-20)
#define FEAT_TILES 3125      // N_NODES/16
#define BF_GRID 2346         // 1564 scatter + 782 feat blocks, interleaved %3

typedef unsigned int uint32;
typedef unsigned short ushort16;
typedef short bf8v __attribute__((ext_vector_type(8)));   // 8 bf16 (4 VGPRs)
typedef float f32x4 __attribute__((ext_vector_type(4)));

// fp32 -> bf16 bits, round-to-nearest-even
__device__ __forceinline__ ushort16 f2bf(float f) {
  uint32 u = __float_as_uint(f);
  u += 0x7fffu + ((u >> 16) & 1u);
  return (ushort16)(u >> 16);
}

// ---- D1: blocks 0..63: W1[64][256] -> w1t bf16 [256][64]. Blocks 64..112:
// zero deg. Blocks 113..116: wlr[col][k] = sum_o W1[k,h,o]*a(l/r)1[h,o]
// (col = h for el, 8+h for er) -> bf16 [16][64]. ----
__global__ __launch_bounds__(256) void k_init(const float* __restrict__ W1,
    const float* __restrict__ al1, const float* __restrict__ ar1,
    ushort16* __restrict__ w1t, ushort16* __restrict__ wlr,
    int4* __restrict__ deg4) {
  int b = blockIdx.x, t = threadIdx.x;
  if (b < 64) {
    int col = b * 4 + (t >> 6), k = t & 63;
    w1t[col * 64 + k] = f2bf(W1[k * 256 + col]);
  } else if (b < 113) {
    int i = (b - 64) * 256 + t;  // int4 index; 12500 total
    if (i < 12500) deg4[i] = make_int4(0, 0, 0, 0);
  } else {
    int id = (b - 113) * 256 + t;  // 0..1023 = 16 cols x 64 k
    if (id < 1024) {
      int col = id >> 6, k = id & 63;
      const float* av = (col < 8) ? al1 : ar1;
      int h = col & 7;
      float s = 0.f;
#pragma unroll
      for (int o = 0; o < 32; ++o)
        s += W1[k * 256 + h * 32 + o] * av[h * 32 + o];
      wlr[col * 64 + k] = f2bf(s);
    }
  }
}

// ---- D2: interleaved merged dispatch. Scatter role (%3 != 2): bucket build.
// Feat role (%3 == 2): per 16-node tile: quantize x -> fp8 x8 (64B rows) AND
// 2-MFMA mini-GEMM x @ wlr -> el1|er1 (the full feature GEMM is deferred to
// k_agg1's epilogue via sum_j a_j (x_j W1) = (sum_j a_j x_j) W1). ----
__global__ __launch_bounds__(256) void k_build_feat(const float* __restrict__ x,
    const ushort16* __restrict__ wlr, float* __restrict__ el1,
    float* __restrict__ er1, uint2* __restrict__ x8w,
    const int* __restrict__ src, const int* __restrict__ dst,
    int* __restrict__ deg, unsigned short* __restrict__ esrc16) {
  int t = threadIdx.x;
  int r3 = blockIdx.x % 3;
  if (r3 != 2) {  // ---- scatter-build role: 2 independent edges/thread ----
    int sid = (blockIdx.x / 3) * 2 + r3;
    int e0 = sid * 512 + t;
    int e1 = e0 + 256;
    if (e0 < N_EDGES) {
      int d0 = __builtin_nontemporal_load(dst + e0);
      int s0 = __builtin_nontemporal_load(src + e0);
      int p0 = atomicAdd(&deg[d0], 1);
      if (p0 < CAP) esrc16[d0 * CAP + p0] = (unsigned short)s0;
    }
    if (e1 < N_EDGES) {
      int d1 = __builtin_nontemporal_load(dst + e1);
      int s1 = __builtin_nontemporal_load(src + e1);
      int p1 = atomicAdd(&deg[d1], 1);
      if (p1 < CAP) esrc16[d1 * CAP + p1] = (unsigned short)s1;
    }
    return;
  }
  // ---- feat role: 4 waves x one 16-node tile each ----
  int fid = blockIdx.x / 3;
  int w = t >> 6, lane = t & 63, quad = lane >> 4, m = lane & 15;
  int tile = fid * 4 + w;
  if (tile >= FEAT_TILES) return;
  int n0 = tile * 16;
  const float* xr = x + (n0 + m) * 64 + quad * 8;
  float4 xa = *(const float4*)(xr);
  float4 xb = *(const float4*)(xr + 4);
  float4 xc = *(const float4*)(xr + 32);
  float4 xd = *(const float4*)(xr + 36);
  // fp8 x8 store (row n: 64 bytes; this lane: bytes quad*8..+7 and +32..+39)
  uint32 p0 = (uint32)__builtin_amdgcn_cvt_pk_fp8_f32(xa.x, xa.y, 0, 0);
  p0 = (uint32)__builtin_amdgcn_cvt_pk_fp8_f32(xa.z, xa.w, p0, 1);
  uint32 p1 = (uint32)__builtin_amdgcn_cvt_pk_fp8_f32(xb.x, xb.y, 0, 0);
  p1 = (uint32)__builtin_amdgcn_cvt_pk_fp8_f32(xb.z, xb.w, p1, 1);
  uint32 p2 = (uint32)__builtin_amdgcn_cvt_pk_fp8_f32(xc.x, xc.y, 0, 0);
  p2 = (uint32)__builtin_amdgcn_cvt_pk_fp8_f32(xc.z, xc.w, p2, 1);
  uint32 p3 = (uint32)__builtin_amdgcn_cvt_pk_fp8_f32(xd.x, xd.y, 0, 0);
  p3 = (uint32)__builtin_amdgcn_cvt_pk_fp8_f32(xd.z, xd.w, p3, 1);
  uint2* xo = x8w + (size_t)(n0 + m) * 8 + quad;
  xo[0] = make_uint2(p0, p1);
  xo[4] = make_uint2(p2, p3);
  // bf16 A-frags (verified pattern: lane(quad,m) holds row n0+m, k=quad*8../+32)
  bf8v a0, a1;
  a0[0] = (short)f2bf(xa.x); a0[1] = (short)f2bf(xa.y);
  a0[2] = (short)f2bf(xa.z); a0[3] = (short)f2bf(xa.w);
  a0[4] = (short)f2bf(xb.x); a0[5] = (short)f2bf(xb.y);
  a0[6] = (short)f2bf(xb.z); a0[7] = (short)f2bf(xb.w);
  a1[0] = (short)f2bf(xc.x); a1[1] = (short)f2bf(xc.y);
  a1[2] = (short)f2bf(xc.z); a1[3] = (short)f2bf(xc.w);
  a1[4] = (short)f2bf(xd.x); a1[5] = (short)f2bf(xd.y);
  a1[6] = (short)f2bf(xd.z); a1[7] = (short)f2bf(xd.w);
  const bf8v* bwp = (const bf8v*)(wlr + m * 64 + quad * 8);
  bf8v b0 = bwp[0], b4 = bwp[4];
  f32x4 acc = {0.f, 0.f, 0.f, 0.f};
  acc = __builtin_amdgcn_mfma_f32_16x16x32_bf16(a0, b0, acc, 0, 0, 0);
  acc = __builtin_amdgcn_mfma_f32_16x16x32_bf16(a1, b4, acc, 0, 0, 0);
  // C layout: row = quad*4+i (node), col = m: m<8 -> el head m, else er head m-8
#pragma unroll
  for (int i = 0; i < 4; ++i) {
    int node = n0 + quad * 4 + i;
    if (m < 8) el1[node * 8 + m] = acc[i];
    else       er1[node * 8 + (m - 8)] = acc[i];
  }
}

// unpack 16 fp8 (uint4) -> scaled accumulate into acc[B..B+15]
#define ACC16(U, EX, B)                                                  \
  {                                                                      \
    auto q0 = __builtin_amdgcn_cvt_pk_f32_fp8((U).x, 0);                 \
    auto q1 = __builtin_amdgcn_cvt_pk_f32_fp8((U).x, 1);                 \
    auto q2 = __builtin_amdgcn_cvt_pk_f32_fp8((U).y, 0);                 \
    auto q3 = __builtin_amdgcn_cvt_pk_f32_fp8((U).y, 1);                 \
    auto q4 = __builtin_amdgcn_cvt_pk_f32_fp8((U).z, 0);                 \
    auto q5 = __builtin_amdgcn_cvt_pk_f32_fp8((U).z, 1);                 \
    auto q6 = __builtin_amdgcn_cvt_pk_f32_fp8((U).w, 0);                 \
    auto q7 = __builtin_amdgcn_cvt_pk_f32_fp8((U).w, 1);                 \
    acc[(B) + 0] += q0[0] * (EX);  acc[(B) + 1] += q0[1] * (EX);         \
    acc[(B) + 2] += q1[0] * (EX);  acc[(B) + 3] += q1[1] * (EX);         \
    acc[(B) + 4] += q2[0] * (EX);  acc[(B) + 5] += q2[1] * (EX);         \
    acc[(B) + 6] += q3[0] * (EX);  acc[(B) + 7] += q3[1] * (EX);         \
    acc[(B) + 8] += q4[0] * (EX);  acc[(B) + 9] += q4[1] * (EX);         \
    acc[(B) + 10] += q5[0] * (EX); acc[(B) + 11] += q5[1] * (EX);        \
    acc[(B) + 12] += q6[0] * (EX); acc[(B) + 13] += q6[1] * (EX);        \
    acc[(B) + 14] += q7[0] * (EX); acc[(B) + 15] += q7[1] * (EX);        \
  }

// ---- D3: layer-1 agg: 16 nodes/block, 16 thr/node (thread = head h x feat-
// half). Gather raw-x fp8 rows (64B, L2-resident), softmax-weight in VALU,
// then per-block MFMA epilogue: h = (xagg/s) @ W1, relu(+b1) . W2 -> feat2. ----
__global__ __launch_bounds__(256) void k_agg1(const int* __restrict__ deg,
    const unsigned short* __restrict__ esrc16, const uint4* __restrict__ x8q,
    const float* __restrict__ el1, const float* __restrict__ er1,
    const ushort16* __restrict__ w1t, const float* __restrict__ b1,
    const float* __restrict__ W2, float* __restrict__ feat2) {
  __shared__ uint4 Ab4[1024];     // 16 KiB: A[8 heads][16 nodes][64 feats] bf16
  __shared__ float redw[4][16];
  int t = threadIdx.x, nl = t >> 4, lt = t & 15;
  int h = lt & 7, hf = lt >> 3;   // head, feat-half
  int n = blockIdx.x * 16 + nl;
  float er_h = er1[n * 8 + h];
  int begin = n * CAP;
  int d = deg[n]; d = d > CAP ? CAP : d;
  int end = begin + d;
  float acc[32];
#pragma unroll
  for (int i = 0; i < 32; ++i) acc[i] = 0.f;
  float s = 0.f;
  int e = begin;
  for (; e + 4 <= end; e += 4) {
    uint2 sv = *(const uint2*)(esrc16 + e);   // 4 ushort src ids
    int sn0 = (int)(sv.x & 0xffffu), sn1 = (int)(sv.x >> 16);
    int sn2 = (int)(sv.y & 0xffffu), sn3 = (int)(sv.y >> 16);
    const uint4* r0 = x8q + sn0 * 4 + hf * 2;
    const uint4* r1 = x8q + sn1 * 4 + hf * 2;
    const uint4* r2 = x8q + sn2 * 4 + hf * 2;
    const uint4* r3 = x8q + sn3 * 4 + hf * 2;
    uint4 u0a = r0[0], u0b = r0[1];
    uint4 u1a = r1[0], u1b = r1[1];
    uint4 u2a = r2[0], u2b = r2[1];
    uint4 u3a = r3[0], u3b = r3[1];
    float v0 = el1[sn0 * 8 + h] + er_h;
    float v1 = el1[sn1 * 8 + h] + er_h;
    float v2 = el1[sn2 * 8 + h] + er_h;
    float v3 = el1[sn3 * 8 + h] + er_h;
    v0 = v0 > 0.f ? v0 : 0.2f * v0;
    v1 = v1 > 0.f ? v1 : 0.2f * v1;
    v2 = v2 > 0.f ? v2 : 0.2f * v2;
    v3 = v3 > 0.f ? v3 : 0.2f * v3;
    float x0 = __expf(v0), x1 = __expf(v1), x2 = __expf(v2), x3 = __expf(v3);
    s += x0 + x1 + x2 + x3;
    ACC16(u0a, x0, 0); ACC16(u0b, x0, 16);
    ACC16(u1a, x1, 0); ACC16(u1b, x1, 16);
    ACC16(u2a, x2, 0); ACC16(u2b, x2, 16);
    ACC16(u3a, x3, 0); ACC16(u3b, x3, 16);
  }
  for (; e < end; ++e) {
    int sN = (int)esrc16[e];
    const uint4* rp = x8q + sN * 4 + hf * 2;
    uint4 ua = rp[0], ub = rp[1];
    float v = el1[sN * 8 + h] + er_h;
    v = v > 0.f ? v : 0.2f * v;
    float ex = __expf(v);
    s += ex;
    ACC16(ua, ex, 0); ACC16(ub, ex, 16);
  }
  float inv = (d > 0) ? 1.f / s : 0.f;
  // stage scaled xagg to LDS as bf16, XOR-swizzled (key = (row+2h)&7, applied
  // identically on write and read -> bijective within each 128B row)
  char* lb = (char*)Ab4 + h * 2048 + nl * 128;
  int swz = ((nl + 2 * h) & 7) << 4;
#pragma unroll
  for (int c = 0; c < 4; ++c) {
    uint4 pk;
    pk.x = (uint32)f2bf(acc[c * 8 + 0] * inv) | ((uint32)f2bf(acc[c * 8 + 1] * inv) << 16);
    pk.y = (uint32)f2bf(acc[c * 8 + 2] * inv) | ((uint32)f2bf(acc[c * 8 + 3] * inv) << 16);
    pk.z = (uint32)f2bf(acc[c * 8 + 4] * inv) | ((uint32)f2bf(acc[c * 8 + 5] * inv) << 16);
    pk.w = (uint32)f2bf(acc[c * 8 + 6] * inv) | ((uint32)f2bf(acc[c * 8 + 7] * inv) << 16);
    *(uint4*)(lb + ((hf * 64 + c * 16) ^ swz)) = pk;
  }
  __syncthreads();
  // ---- MFMA epilogue: wave w handles heads 2w, 2w+1 ----
  int w = t >> 6, lane = t & 63, quad = lane >> 4, m = lane & 15;
  float rsum[4] = {0.f, 0.f, 0.f, 0.f};
#pragma unroll
  for (int hh = 0; hh < 2; ++hh) {
    int hq = w * 2 + hh;
    const char* ab = (const char*)Ab4 + hq * 2048 + m * 128;
    int sw2 = ((m + 2 * hq) & 7) << 4;
    bf8v af0 = *(const bf8v*)(ab + ((quad * 16) ^ sw2));
    bf8v af1 = *(const bf8v*)(ab + ((64 + quad * 16) ^ sw2));
#pragma unroll
    for (int ct = 0; ct < 2; ++ct) {
      int colg = hq * 32 + ct * 16 + m;
      const bf8v* bw = (const bf8v*)(w1t + colg * 64 + quad * 8);
      bf8v bf0 = bw[0], bf4 = bw[4];
      f32x4 c2 = {0.f, 0.f, 0.f, 0.f};
      c2 = __builtin_amdgcn_mfma_f32_16x16x32_bf16(af0, bf0, c2, 0, 0, 0);
      c2 = __builtin_amdgcn_mfma_f32_16x16x32_bf16(af1, bf4, c2, 0, 0, 0);
      float bb = b1[colg], w2v = W2[colg];
#pragma unroll
      for (int i = 0; i < 4; ++i)
        rsum[i] += fmaxf(c2[i] + bb, 0.f) * w2v;
    }
  }
#pragma unroll
  for (int off = 1; off < 16; off <<= 1) {
#pragma unroll
    for (int i = 0; i < 4; ++i) rsum[i] += __shfl_xor(rsum[i], off, 16);
  }
  if (m == 0) {
#pragma unroll
    for (int i = 0; i < 4; ++i) redw[w][quad * 4 + i] = rsum[i];
  }
  __syncthreads();
  if (t < 16)
    feat2[blockIdx.x * 16 + t] = redw[0][t] + redw[1][t] + redw[2][t] + redw[3][t];
}

// ---- D4: layer-2 fused (el2/er2 on the fly; one gather per edge), sigmoid ----
__global__ __launch_bounds__(256) void k_layer2(const int* __restrict__ deg,
    const unsigned short* __restrict__ esrc16, const float* __restrict__ feat2,
    const float* __restrict__ al2, const float* __restrict__ ar2,
    const float* __restrict__ b2, float* __restrict__ out) {
  int t = threadIdx.x, g = t >> 4, lt = t & 15;
  int n = blockIdx.x * 16 + g;
  int begin = n * CAP;
  int d = deg[n]; d = d > CAP ? CAP : d;
  int end = begin + d;
  float a2 = al2[0];
  float er_n = feat2[n] * ar2[0];
  float num = 0.f, s = 0.f;
  for (int e = begin + lt; e < end; e += 16) {
    int sN = (int)esrc16[e];
    float f = feat2[sN];
    float v = f * a2 + er_n;
    v = v > 0.f ? v : 0.2f * v;
    float ex = __expf(v);
    num += f * ex;
    s += ex;
  }
#pragma unroll
  for (int off = 8; off > 0; off >>= 1) {
    num += __shfl_down(num, off, 16);
    s += __shfl_down(s, off, 16);
  }
  if (lt == 0) {
    float val = (d > 0) ? num / s : 0.f;
    out[n] = 1.f / (1.f + __expf(-(val + b2[0])));
  }
}

extern "C" void kernel_launch(void* const* d_in, const int* in_sizes, int n_in,
                              void* d_out, int out_size, void* d_ws, size_t ws_size,
                              hipStream_t stream) {
  const float* x   = (const float*)d_in[0];
  const int* src   = (const int*)d_in[1];
  const int* dst   = (const int*)d_in[2];
  // d_in[3] = edge_types (unused by reference)
  const float* W1  = (const float*)d_in[4];
  const float* al1 = (const float*)d_in[5];
  const float* ar1 = (const float*)d_in[6];
  const float* b1  = (const float*)d_in[7];
  const float* W2  = (const float*)d_in[8];
  const float* al2 = (const float*)d_in[9];
  const float* ar2 = (const float*)d_in[10];
  const float* b2  = (const float*)d_in[11];

  // Workspace (~13.3 MB), offsets in 4-byte words; 16B-aligned segments.
  float* ws    = (float*)d_ws;
  float* el1   = ws;                       //   400,000 f
  float* er1   = ws + 400000;              //   400,000 f
  float* feat2 = ws + 800000;              //    50,000 f
  int* deg     = (int*)ws + 850000;        //    50,000 i (zeroed in k_init)
  unsigned short* esrc16 = (unsigned short*)((int*)ws + 900000);  // 3.2M u16
  ushort16* w1t = (ushort16*)((int*)ws + 2500000);  // 16,384 bf16 -> 2,508,192
  ushort16* wlr = (ushort16*)((int*)ws + 2508192);  //  1,024 bf16 -> 2,508,704
  uint2* x8w    = (uint2*)((int*)ws + 2508704);     // 3.2M fp8 -> 3,308,704

  k_init<<<117, 256, 0, stream>>>(W1, al1, ar1, w1t, wlr, (int4*)deg);
  k_build_feat<<<BF_GRID, 256, 0, stream>>>(x, wlr, el1, er1, x8w, src, dst,
                                            deg, esrc16);
  k_agg1<<<N_NODES / 16, 256, 0, stream>>>(deg, esrc16, (const uint4*)x8w,
                                           el1, er1, w1t, b1, W2, feat2);
  k_layer2<<<N_NODES / 16, 256, 0, stream>>>(deg, esrc16, feat2, al2, ar2, b2,
                                             (float*)d_out);
}

// Round 12
// 217.363 us; speedup vs baseline: 1.0156x; 1.0156x over previous
//
#include <hip/hip_runtime.h>

#define N_NODES 50000
#define N_EDGES 800000
#define CAP 64               // per-node bucket capacity (Poisson(16): P(>64)~1e-20)
#define FEAT_TILES 3125      // N_NODES/16
#define BF_GRID 1564         // 782 scatter + 782 feat blocks, parity-interleaved

typedef unsigned int uint32;
typedef unsigned short ushort16;
typedef short bf8v __attribute__((ext_vector_type(8)));   // 8 bf16 (4 VGPRs)
typedef float f32x4 __attribute__((ext_vector_type(4)));

// fp32 -> bf16 bits, round-to-nearest-even
__device__ __forceinline__ ushort16 f2bf(float f) {
  uint32 u = __float_as_uint(f);
  u += 0x7fffu + ((u >> 16) & 1u);
  return (ushort16)(u >> 16);
}

// ---- D1: blocks 0..63: W1[64][256] -> w1t bf16 [256][64]. Blocks 64..112:
// zero deg. Blocks 113..116: wlr[col][k] = sum_o W1[k,h,o]*a(l/r)1[h,o]
// (col = h for el, 8+h for er) -> bf16 [16][64]. ----
__global__ __launch_bounds__(256) void k_init(const float* __restrict__ W1,
    const float* __restrict__ al1, const float* __restrict__ ar1,
    ushort16* __restrict__ w1t, ushort16* __restrict__ wlr,
    int4* __restrict__ deg4) {
  int b = blockIdx.x, t = threadIdx.x;
  if (b < 64) {
    int col = b * 4 + (t >> 6), k = t & 63;
    w1t[col * 64 + k] = f2bf(W1[k * 256 + col]);
  } else if (b < 113) {
    int i = (b - 64) * 256 + t;  // int4 index; 12500 total
    if (i < 12500) deg4[i] = make_int4(0, 0, 0, 0);
  } else {
    int id = (b - 113) * 256 + t;  // 0..1023 = 16 cols x 64 k
    if (id < 1024) {
      int col = id >> 6, k = id & 63;
      const float* av = (col < 8) ? al1 : ar1;
      int h = col & 7;
      float s = 0.f;
#pragma unroll
      for (int o = 0; o < 32; ++o)
        s += W1[k * 256 + h * 32 + o] * av[h * 32 + o];
      wlr[col * 64 + k] = f2bf(s);
    }
  }
}

// ---- D2: parity-interleaved merged dispatch. Even blocks: bucket build,
// 4 edges/thread via int4 loads (deep atomic ILP). Odd blocks: per 16-node
// tile quantize x -> fp8 (64B rows) + 2-MFMA mini-GEMM x @ wlr -> el1|er1
// (full feature GEMM deferred: sum_j a_j (x_j W1) = (sum_j a_j x_j) W1). ----
__global__ __launch_bounds__(256) void k_build_feat(const float* __restrict__ x,
    const ushort16* __restrict__ wlr, float* __restrict__ el1,
    float* __restrict__ er1, uint2* __restrict__ x8w,
    const int* __restrict__ src, const int* __restrict__ dst,
    int* __restrict__ deg, unsigned short* __restrict__ esrc16) {
  int t = threadIdx.x;
  if ((blockIdx.x & 1) == 0) {  // ---- scatter role: 4 edges/thread ----
    int sid = blockIdx.x >> 1;
    int e0 = sid * 1024 + t * 4;
    if (e0 + 3 < N_EDGES) {
      int4 dv = *(const int4*)(dst + e0);
      int4 sv = *(const int4*)(src + e0);
      int p0 = atomicAdd(&deg[dv.x], 1);
      int p1 = atomicAdd(&deg[dv.y], 1);
      int p2 = atomicAdd(&deg[dv.z], 1);
      int p3 = atomicAdd(&deg[dv.w], 1);
      if (p0 < CAP) esrc16[dv.x * CAP + p0] = (unsigned short)sv.x;
      if (p1 < CAP) esrc16[dv.y * CAP + p1] = (unsigned short)sv.y;
      if (p2 < CAP) esrc16[dv.z * CAP + p2] = (unsigned short)sv.z;
      if (p3 < CAP) esrc16[dv.w * CAP + p3] = (unsigned short)sv.w;
    } else {
      for (int j = 0; j < 4; ++j) {
        int e = e0 + j;
        if (e < N_EDGES) {
          int dd = dst[e], ss = src[e];
          int p = atomicAdd(&deg[dd], 1);
          if (p < CAP) esrc16[dd * CAP + p] = (unsigned short)ss;
        }
      }
    }
    return;
  }
  // ---- feat role: 4 waves x one 16-node tile each ----
  int fid = blockIdx.x >> 1;
  int w = t >> 6, lane = t & 63, quad = lane >> 4, m = lane & 15;
  int tile = fid * 4 + w;
  if (tile >= FEAT_TILES) return;
  int n0 = tile * 16;
  const float* xr = x + (n0 + m) * 64 + quad * 8;
  float4 xa = *(const float4*)(xr);
  float4 xb = *(const float4*)(xr + 4);
  float4 xc = *(const float4*)(xr + 32);
  float4 xd = *(const float4*)(xr + 36);
  // fp8 x8 store (row n: 64 bytes; this lane: bytes quad*8..+7 and +32..+39)
  uint32 p0 = (uint32)__builtin_amdgcn_cvt_pk_fp8_f32(xa.x, xa.y, 0, 0);
  p0 = (uint32)__builtin_amdgcn_cvt_pk_fp8_f32(xa.z, xa.w, p0, 1);
  uint32 p1 = (uint32)__builtin_amdgcn_cvt_pk_fp8_f32(xb.x, xb.y, 0, 0);
  p1 = (uint32)__builtin_amdgcn_cvt_pk_fp8_f32(xb.z, xb.w, p1, 1);
  uint32 p2 = (uint32)__builtin_amdgcn_cvt_pk_fp8_f32(xc.x, xc.y, 0, 0);
  p2 = (uint32)__builtin_amdgcn_cvt_pk_fp8_f32(xc.z, xc.w, p2, 1);
  uint32 p3 = (uint32)__builtin_amdgcn_cvt_pk_fp8_f32(xd.x, xd.y, 0, 0);
  p3 = (uint32)__builtin_amdgcn_cvt_pk_fp8_f32(xd.z, xd.w, p3, 1);
  uint2* xo = x8w + (size_t)(n0 + m) * 8 + quad;
  xo[0] = make_uint2(p0, p1);
  xo[4] = make_uint2(p2, p3);
  // bf16 A-frags (verified pattern: lane(quad,m) holds row n0+m, k=quad*8../+32)
  bf8v a0, a1;
  a0[0] = (short)f2bf(xa.x); a0[1] = (short)f2bf(xa.y);
  a0[2] = (short)f2bf(xa.z); a0[3] = (short)f2bf(xa.w);
  a0[4] = (short)f2bf(xb.x); a0[5] = (short)f2bf(xb.y);
  a0[6] = (short)f2bf(xb.z); a0[7] = (short)f2bf(xb.w);
  a1[0] = (short)f2bf(xc.x); a1[1] = (short)f2bf(xc.y);
  a1[2] = (short)f2bf(xc.z); a1[3] = (short)f2bf(xc.w);
  a1[4] = (short)f2bf(xd.x); a1[5] = (short)f2bf(xd.y);
  a1[6] = (short)f2bf(xd.z); a1[7] = (short)f2bf(xd.w);
  const bf8v* bwp = (const bf8v*)(wlr + m * 64 + quad * 8);
  bf8v b0 = bwp[0], b4 = bwp[4];
  f32x4 acc = {0.f, 0.f, 0.f, 0.f};
  acc = __builtin_amdgcn_mfma_f32_16x16x32_bf16(a0, b0, acc, 0, 0, 0);
  acc = __builtin_amdgcn_mfma_f32_16x16x32_bf16(a1, b4, acc, 0, 0, 0);
  // C layout: row = quad*4+i (node), col = m: m<8 -> el head m, else er head m-8
#pragma unroll
  for (int i = 0; i < 4; ++i) {
    int node = n0 + quad * 4 + i;
    if (m < 8) el1[node * 8 + m] = acc[i];
    else       er1[node * 8 + (m - 8)] = acc[i];
  }
}

// unpack 16 fp8 (uint4) -> scaled accumulate into acc[B..B+15]
#define ACC16(U, EX, B)                                                  \
  {                                                                      \
    auto q0 = __builtin_amdgcn_cvt_pk_f32_fp8((U).x, 0);                 \
    auto q1 = __builtin_amdgcn_cvt_pk_f32_fp8((U).x, 1);                 \
    auto q2 = __builtin_amdgcn_cvt_pk_f32_fp8((U).y, 0);                 \
    auto q3 = __builtin_amdgcn_cvt_pk_f32_fp8((U).y, 1);                 \
    auto q4 = __builtin_amdgcn_cvt_pk_f32_fp8((U).z, 0);                 \
    auto q5 = __builtin_amdgcn_cvt_pk_f32_fp8((U).z, 1);                 \
    auto q6 = __builtin_amdgcn_cvt_pk_f32_fp8((U).w, 0);                 \
    auto q7 = __builtin_amdgcn_cvt_pk_f32_fp8((U).w, 1);                 \
    acc[(B) + 0] += q0[0] * (EX);  acc[(B) + 1] += q0[1] * (EX);         \
    acc[(B) + 2] += q1[0] * (EX);  acc[(B) + 3] += q1[1] * (EX);         \
    acc[(B) + 4] += q2[0] * (EX);  acc[(B) + 5] += q2[1] * (EX);         \
    acc[(B) + 6] += q3[0] * (EX);  acc[(B) + 7] += q3[1] * (EX);         \
    acc[(B) + 8] += q4[0] * (EX);  acc[(B) + 9] += q4[1] * (EX);         \
    acc[(B) + 10] += q5[0] * (EX); acc[(B) + 11] += q5[1] * (EX);        \
    acc[(B) + 12] += q6[0] * (EX); acc[(B) + 13] += q6[1] * (EX);        \
    acc[(B) + 14] += q7[0] * (EX); acc[(B) + 15] += q7[1] * (EX);        \
  }

// 4-edge group body (shared by both ep lanes)
#define EDGE4(E)                                                         \
  {                                                                      \
    uint2 sv = *(const uint2*)(esrc16 + (E));                            \
    int sn0 = (int)(sv.x & 0xffffu), sn1 = (int)(sv.x >> 16);            \
    int sn2 = (int)(sv.y & 0xffffu), sn3 = (int)(sv.y >> 16);            \
    const uint4* r0 = x8q + sn0 * 4 + hf * 2;                            \
    const uint4* r1 = x8q + sn1 * 4 + hf * 2;                            \
    const uint4* r2 = x8q + sn2 * 4 + hf * 2;                            \
    const uint4* r3 = x8q + sn3 * 4 + hf * 2;                            \
    uint4 u0a = r0[0], u0b = r0[1];                                      \
    uint4 u1a = r1[0], u1b = r1[1];                                      \
    uint4 u2a = r2[0], u2b = r2[1];                                      \
    uint4 u3a = r3[0], u3b = r3[1];                                      \
    float v0 = el1[sn0 * 8 + h] + er_h;                                  \
    float v1 = el1[sn1 * 8 + h] + er_h;                                  \
    float v2 = el1[sn2 * 8 + h] + er_h;                                  \
    float v3 = el1[sn3 * 8 + h] + er_h;                                  \
    v0 = v0 > 0.f ? v0 : 0.2f * v0;                                      \
    v1 = v1 > 0.f ? v1 : 0.2f * v1;                                      \
    v2 = v2 > 0.f ? v2 : 0.2f * v2;                                      \
    v3 = v3 > 0.f ? v3 : 0.2f * v3;                                      \
    float x0 = __expf(v0), x1 = __expf(v1), x2 = __expf(v2),             \
          x3 = __expf(v3);                                               \
    s += x0 + x1 + x2 + x3;                                              \
    ACC16(u0a, x0, 0); ACC16(u0b, x0, 16);                               \
    ACC16(u1a, x1, 0); ACC16(u1b, x1, 16);                               \
    ACC16(u2a, x2, 0); ACC16(u2b, x2, 16);                               \
    ACC16(u3a, x3, 0); ACC16(u3b, x3, 16);                               \
  }

// ---- D3: layer-1 agg: 16 nodes/block (512 thr), 32 thr/node = head h x
// feat-half hf x edge-parity ep. The two ep lanes process alternating 4-edge
// groups (serial chain halved vs one lane walking all edges), partials merged
// via shfl_xor(16). Then per-block MFMA epilogue:
// h = (xagg/s) @ W1, relu(+b1) . W2 -> feat2. ----
__global__ __launch_bounds__(512) void k_agg1(const int* __restrict__ deg,
    const unsigned short* __restrict__ esrc16, const uint4* __restrict__ x8q,
    const float* __restrict__ el1, const float* __restrict__ er1,
    const ushort16* __restrict__ w1t, const float* __restrict__ b1,
    const float* __restrict__ W2, float* __restrict__ feat2) {
  __shared__ uint4 Ab4[1024];     // 16 KiB: A[8 heads][16 nodes][64 feats] bf16
  __shared__ float redw[8][16];
  int t = threadIdx.x, nl = t >> 5, lt = t & 31;
  int h = lt & 7, hf = (lt >> 3) & 1, ep = lt >> 4;  // head, feat-half, parity
  int n = blockIdx.x * 16 + nl;
  float er_h = er1[n * 8 + h];
  int begin = n * CAP;
  int d = deg[n]; d = d > CAP ? CAP : d;
  float acc[32];
#pragma unroll
  for (int i = 0; i < 32; ++i) acc[i] = 0.f;
  float s = 0.f;
  int G = d >> 2;                  // full 4-edge groups
  for (int g = ep; g < G; g += 2) EDGE4(begin + g * 4);
  if (ep == (G & 1)) {             // tail (<=3 edges) to the "next-turn" lane
    for (int e = begin + G * 4; e < begin + d; ++e) {
      int sN = (int)esrc16[e];
      const uint4* rp = x8q + sN * 4 + hf * 2;
      uint4 ua = rp[0], ub = rp[1];
      float v = el1[sN * 8 + h] + er_h;
      v = v > 0.f ? v : 0.2f * v;
      float ex = __expf(v);
      s += ex;
      ACC16(ua, ex, 0); ACC16(ub, ex, 16);
    }
  }
  // merge the two edge-parity partials (lane ^ 16 = same node/head/half)
  s += __shfl_xor(s, 16, 64);
#pragma unroll
  for (int i = 0; i < 32; ++i) acc[i] += __shfl_xor(acc[i], 16, 64);
  float inv = (d > 0) ? 1.f / s : 0.f;
  // stage scaled xagg to LDS as bf16, XOR-swizzled (key = (row+2h)&7, applied
  // identically on write and read -> bijective within each 128B row).
  // ep==0 lanes only: all c indices compile-time (no runtime reg-array idx).
  if (ep == 0) {
    char* lb = (char*)Ab4 + h * 2048 + nl * 128;
    int swz = ((nl + 2 * h) & 7) << 4;
#pragma unroll
    for (int c = 0; c < 4; ++c) {
      uint4 pk;
      pk.x = (uint32)f2bf(acc[c * 8 + 0] * inv) | ((uint32)f2bf(acc[c * 8 + 1] * inv) << 16);
      pk.y = (uint32)f2bf(acc[c * 8 + 2] * inv) | ((uint32)f2bf(acc[c * 8 + 3] * inv) << 16);
      pk.z = (uint32)f2bf(acc[c * 8 + 4] * inv) | ((uint32)f2bf(acc[c * 8 + 5] * inv) << 16);
      pk.w = (uint32)f2bf(acc[c * 8 + 6] * inv) | ((uint32)f2bf(acc[c * 8 + 7] * inv) << 16);
      *(uint4*)(lb + ((hf * 64 + c * 16) ^ swz)) = pk;
    }
  }
  __syncthreads();
  // ---- MFMA epilogue: 8 waves, wave w handles head w ----
  int w = t >> 6, lane = t & 63, quad = lane >> 4, m = lane & 15;
  float rsum[4] = {0.f, 0.f, 0.f, 0.f};
  const char* ab = (const char*)Ab4 + w * 2048 + m * 128;
  int sw2 = ((m + 2 * w) & 7) << 4;
  bf8v af0 = *(const bf8v*)(ab + ((quad * 16) ^ sw2));
  bf8v af1 = *(const bf8v*)(ab + ((64 + quad * 16) ^ sw2));
#pragma unroll
  for (int ct = 0; ct < 2; ++ct) {
    int colg = w * 32 + ct * 16 + m;
    const bf8v* bw = (const bf8v*)(w1t + colg * 64 + quad * 8);
    bf8v bf0 = bw[0], bf4 = bw[4];
    f32x4 c2 = {0.f, 0.f, 0.f, 0.f};
    c2 = __builtin_amdgcn_mfma_f32_16x16x32_bf16(af0, bf0, c2, 0, 0, 0);
    c2 = __builtin_amdgcn_mfma_f32_16x16x32_bf16(af1, bf4, c2, 0, 0, 0);
    float bb = b1[colg], w2v = W2[colg];
#pragma unroll
    for (int i = 0; i < 4; ++i)
      rsum[i] += fmaxf(c2[i] + bb, 0.f) * w2v;
  }
#pragma unroll
  for (int off = 1; off < 16; off <<= 1) {
#pragma unroll
    for (int i = 0; i < 4; ++i) rsum[i] += __shfl_xor(rsum[i], off, 16);
  }
  if (m == 0) {
#pragma unroll
    for (int i = 0; i < 4; ++i) redw[w][quad * 4 + i] = rsum[i];
  }
  __syncthreads();
  if (t < 16) {
    float r = redw[0][t] + redw[1][t] + redw[2][t] + redw[3][t]
            + redw[4][t] + redw[5][t] + redw[6][t] + redw[7][t];
    feat2[blockIdx.x * 16 + t] = r;
  }
}

// ---- D4: layer-2 fused (el2/er2 on the fly; one gather per edge), sigmoid ----
__global__ __launch_bounds__(256) void k_layer2(const int* __restrict__ deg,
    const unsigned short* __restrict__ esrc16, const float* __restrict__ feat2,
    const float* __restrict__ al2, const float* __restrict__ ar2,
    const float* __restrict__ b2, float* __restrict__ out) {
  int t = threadIdx.x, g = t >> 4, lt = t & 15;
  int n = blockIdx.x * 16 + g;
  int begin = n * CAP;
  int d = deg[n]; d = d > CAP ? CAP : d;
  int end = begin + d;
  float a2 = al2[0];
  float er_n = feat2[n] * ar2[0];
  float num = 0.f, s = 0.f;
  for (int e = begin + lt; e < end; e += 16) {
    int sN = (int)esrc16[e];
    float f = feat2[sN];
    float v = f * a2 + er_n;
    v = v > 0.f ? v : 0.2f * v;
    float ex = __expf(v);
    num += f * ex;
    s += ex;
  }
#pragma unroll
  for (int off = 8; off > 0; off >>= 1) {
    num += __shfl_down(num, off, 16);
    s += __shfl_down(s, off, 16);
  }
  if (lt == 0) {
    float val = (d > 0) ? num / s : 0.f;
    out[n] = 1.f / (1.f + __expf(-(val + b2[0])));
  }
}

extern "C" void kernel_launch(void* const* d_in, const int* in_sizes, int n_in,
                              void* d_out, int out_size, void* d_ws, size_t ws_size,
                              hipStream_t stream) {
  const float* x   = (const float*)d_in[0];
  const int* src   = (const int*)d_in[1];
  const int* dst   = (const int*)d_in[2];
  // d_in[3] = edge_types (unused by reference)
  const float* W1  = (const float*)d_in[4];
  const float* al1 = (const float*)d_in[5];
  const float* ar1 = (const float*)d_in[6];
  const float* b1  = (const float*)d_in[7];
  const float* W2  = (const float*)d_in[8];
  const float* al2 = (const float*)d_in[9];
  const float* ar2 = (const float*)d_in[10];
  const float* b2  = (const float*)d_in[11];

  // Workspace (~13.3 MB), offsets in 4-byte words; 16B-aligned segments.
  float* ws    = (float*)d_ws;
  float* el1   = ws;                       //   400,000 f
  float* er1   = ws + 400000;              //   400,000 f
  float* feat2 = ws + 800000;              //    50,000 f
  int* deg     = (int*)ws + 850000;        //    50,000 i (zeroed in k_init)
  unsigned short* esrc16 = (unsigned short*)((int*)ws + 900000);  // 3.2M u16
  ushort16* w1t = (ushort16*)((int*)ws + 2500000);  // 16,384 bf16 -> 2,508,192
  ushort16* wlr = (ushort16*)((int*)ws + 2508192);  //  1,024 bf16 -> 2,508,704
  uint2* x8w    = (uint2*)((int*)ws + 2508704);     // 3.2M fp8 -> 3,308,704

  k_init<<<117, 256, 0, stream>>>(W1, al1, ar1, w1t, wlr, (int4*)deg);
  k_build_feat<<<BF_GRID, 256, 0, stream>>>(x, wlr, el1, er1, x8w, src, dst,
                                            deg, esrc16);
  k_agg1<<<N_NODES / 16, 512, 0, stream>>>(deg, esrc16, (const uint4*)x8w,
                                           el1, er1, w1t, b1, W2, feat2);
  k_layer2<<<N_NODES / 16, 256, 0, stream>>>(deg, esrc16, feat2, al2, ar2, b2,
                                             (float*)d_out);
}

// Round 13
// 212.068 us; speedup vs baseline: 1.0410x; 1.0250x over previous
//
#include <hip/hip_runtime.h>

#define N_NODES 50000
#define N_EDGES 800000
#define CAP 64               // per-node bucket capacity (Poisson(16): P(>64)~1e-20)
#define FEAT_TILES 3125      // N_NODES/16
#define BF_GRID 1564         // 782 scatter + 782 feat blocks, parity-interleaved

typedef unsigned int uint32;
typedef unsigned short ushort16;
typedef short bf8v __attribute__((ext_vector_type(8)));   // 8 bf16 (4 VGPRs)
typedef float f32x4 __attribute__((ext_vector_type(4)));

// fp32 -> bf16 bits, round-to-nearest-even
__device__ __forceinline__ ushort16 f2bf(float f) {
  uint32 u = __float_as_uint(f);
  u += 0x7fffu + ((u >> 16) & 1u);
  return (ushort16)(u >> 16);
}

// ---- D1: blocks 0..63: W1[64][256] -> w1t bf16 [256][64]. Blocks 64..112:
// zero deg. Blocks 113..116: wlr[col][k] = sum_o W1[k,h,o]*a(l/r)1[h,o]
// (col = h for el, 8+h for er) -> bf16 [16][64]. ----
__global__ __launch_bounds__(256) void k_init(const float* __restrict__ W1,
    const float* __restrict__ al1, const float* __restrict__ ar1,
    ushort16* __restrict__ w1t, ushort16* __restrict__ wlr,
    int4* __restrict__ deg4) {
  int b = blockIdx.x, t = threadIdx.x;
  if (b < 64) {
    int col = b * 4 + (t >> 6), k = t & 63;
    w1t[col * 64 + k] = f2bf(W1[k * 256 + col]);
  } else if (b < 113) {
    int i = (b - 64) * 256 + t;  // int4 index; 12500 total
    if (i < 12500) deg4[i] = make_int4(0, 0, 0, 0);
  } else {
    int id = (b - 113) * 256 + t;  // 0..1023 = 16 cols x 64 k
    if (id < 1024) {
      int col = id >> 6, k = id & 63;
      const float* av = (col < 8) ? al1 : ar1;
      int h = col & 7;
      float s = 0.f;
#pragma unroll
      for (int o = 0; o < 32; ++o)
        s += W1[k * 256 + h * 32 + o] * av[h * 32 + o];
      wlr[col * 64 + k] = f2bf(s);
    }
  }
}

// ---- D2: parity-interleaved merged dispatch. Even blocks: bucket build,
// 4 edges/thread via int4 loads (deep atomic ILP). Odd blocks: per 16-node
// tile quantize x -> fp8 (64B rows) + 2-MFMA mini-GEMM x @ wlr -> el1|er1
// (full feature GEMM deferred: sum_j a_j (x_j W1) = (sum_j a_j x_j) W1). ----
__global__ __launch_bounds__(256) void k_build_feat(const float* __restrict__ x,
    const ushort16* __restrict__ wlr, float* __restrict__ el1,
    float* __restrict__ er1, uint2* __restrict__ x8w,
    const int* __restrict__ src, const int* __restrict__ dst,
    int* __restrict__ deg, unsigned short* __restrict__ esrc16) {
  int t = threadIdx.x;
  if ((blockIdx.x & 1) == 0) {  // ---- scatter role: 4 edges/thread ----
    int sid = blockIdx.x >> 1;
    int e0 = sid * 1024 + t * 4;
    if (e0 + 3 < N_EDGES) {
      int4 dv = *(const int4*)(dst + e0);
      int4 sv = *(const int4*)(src + e0);
      int p0 = atomicAdd(&deg[dv.x], 1);
      int p1 = atomicAdd(&deg[dv.y], 1);
      int p2 = atomicAdd(&deg[dv.z], 1);
      int p3 = atomicAdd(&deg[dv.w], 1);
      if (p0 < CAP) esrc16[dv.x * CAP + p0] = (unsigned short)sv.x;
      if (p1 < CAP) esrc16[dv.y * CAP + p1] = (unsigned short)sv.y;
      if (p2 < CAP) esrc16[dv.z * CAP + p2] = (unsigned short)sv.z;
      if (p3 < CAP) esrc16[dv.w * CAP + p3] = (unsigned short)sv.w;
    } else {
      for (int j = 0; j < 4; ++j) {
        int e = e0 + j;
        if (e < N_EDGES) {
          int dd = dst[e], ss = src[e];
          int p = atomicAdd(&deg[dd], 1);
          if (p < CAP) esrc16[dd * CAP + p] = (unsigned short)ss;
        }
      }
    }
    return;
  }
  // ---- feat role: 4 waves x one 16-node tile each ----
  int fid = blockIdx.x >> 1;
  int w = t >> 6, lane = t & 63, quad = lane >> 4, m = lane & 15;
  int tile = fid * 4 + w;
  if (tile >= FEAT_TILES) return;
  int n0 = tile * 16;
  const float* xr = x + (n0 + m) * 64 + quad * 8;
  float4 xa = *(const float4*)(xr);
  float4 xb = *(const float4*)(xr + 4);
  float4 xc = *(const float4*)(xr + 32);
  float4 xd = *(const float4*)(xr + 36);
  // fp8 x8 store (row n: 64 bytes; this lane: bytes quad*8..+7 and +32..+39)
  uint32 p0 = (uint32)__builtin_amdgcn_cvt_pk_fp8_f32(xa.x, xa.y, 0, 0);
  p0 = (uint32)__builtin_amdgcn_cvt_pk_fp8_f32(xa.z, xa.w, p0, 1);
  uint32 p1 = (uint32)__builtin_amdgcn_cvt_pk_fp8_f32(xb.x, xb.y, 0, 0);
  p1 = (uint32)__builtin_amdgcn_cvt_pk_fp8_f32(xb.z, xb.w, p1, 1);
  uint32 p2 = (uint32)__builtin_amdgcn_cvt_pk_fp8_f32(xc.x, xc.y, 0, 0);
  p2 = (uint32)__builtin_amdgcn_cvt_pk_fp8_f32(xc.z, xc.w, p2, 1);
  uint32 p3 = (uint32)__builtin_amdgcn_cvt_pk_fp8_f32(xd.x, xd.y, 0, 0);
  p3 = (uint32)__builtin_amdgcn_cvt_pk_fp8_f32(xd.z, xd.w, p3, 1);
  uint2* xo = x8w + (size_t)(n0 + m) * 8 + quad;
  xo[0] = make_uint2(p0, p1);
  xo[4] = make_uint2(p2, p3);
  // bf16 A-frags (verified pattern: lane(quad,m) holds row n0+m, k=quad*8../+32)
  bf8v a0, a1;
  a0[0] = (short)f2bf(xa.x); a0[1] = (short)f2bf(xa.y);
  a0[2] = (short)f2bf(xa.z); a0[3] = (short)f2bf(xa.w);
  a0[4] = (short)f2bf(xb.x); a0[5] = (short)f2bf(xb.y);
  a0[6] = (short)f2bf(xb.z); a0[7] = (short)f2bf(xb.w);
  a1[0] = (short)f2bf(xc.x); a1[1] = (short)f2bf(xc.y);
  a1[2] = (short)f2bf(xc.z); a1[3] = (short)f2bf(xc.w);
  a1[4] = (short)f2bf(xd.x); a1[5] = (short)f2bf(xd.y);
  a1[6] = (short)f2bf(xd.z); a1[7] = (short)f2bf(xd.w);
  const bf8v* bwp = (const bf8v*)(wlr + m * 64 + quad * 8);
  bf8v b0 = bwp[0], b4 = bwp[4];
  f32x4 acc = {0.f, 0.f, 0.f, 0.f};
  acc = __builtin_amdgcn_mfma_f32_16x16x32_bf16(a0, b0, acc, 0, 0, 0);
  acc = __builtin_amdgcn_mfma_f32_16x16x32_bf16(a1, b4, acc, 0, 0, 0);
  // C layout: row = quad*4+i (node), col = m: m<8 -> el head m, else er head m-8
#pragma unroll
  for (int i = 0; i < 4; ++i) {
    int node = n0 + quad * 4 + i;
    if (m < 8) el1[node * 8 + m] = acc[i];
    else       er1[node * 8 + (m - 8)] = acc[i];
  }
}

// unpack 16 fp8 (uint4) -> scaled accumulate into acc[B..B+15]
#define ACC16(U, EX, B)                                                  \
  {                                                                      \
    auto q0 = __builtin_amdgcn_cvt_pk_f32_fp8((U).x, 0);                 \
    auto q1 = __builtin_amdgcn_cvt_pk_f32_fp8((U).x, 1);                 \
    auto q2 = __builtin_amdgcn_cvt_pk_f32_fp8((U).y, 0);                 \
    auto q3 = __builtin_amdgcn_cvt_pk_f32_fp8((U).y, 1);                 \
    auto q4 = __builtin_amdgcn_cvt_pk_f32_fp8((U).z, 0);                 \
    auto q5 = __builtin_amdgcn_cvt_pk_f32_fp8((U).z, 1);                 \
    auto q6 = __builtin_amdgcn_cvt_pk_f32_fp8((U).w, 0);                 \
    auto q7 = __builtin_amdgcn_cvt_pk_f32_fp8((U).w, 1);                 \
    acc[(B) + 0] += q0[0] * (EX);  acc[(B) + 1] += q0[1] * (EX);         \
    acc[(B) + 2] += q1[0] * (EX);  acc[(B) + 3] += q1[1] * (EX);         \
    acc[(B) + 4] += q2[0] * (EX);  acc[(B) + 5] += q2[1] * (EX);         \
    acc[(B) + 6] += q3[0] * (EX);  acc[(B) + 7] += q3[1] * (EX);         \
    acc[(B) + 8] += q4[0] * (EX);  acc[(B) + 9] += q4[1] * (EX);         \
    acc[(B) + 10] += q5[0] * (EX); acc[(B) + 11] += q5[1] * (EX);        \
    acc[(B) + 12] += q6[0] * (EX); acc[(B) + 13] += q6[1] * (EX);        \
    acc[(B) + 14] += q7[0] * (EX); acc[(B) + 15] += q7[1] * (EX);        \
  }

// 4-edge group body (shared by both ep lanes)
#define EDGE4(E)                                                         \
  {                                                                      \
    uint2 sv = *(const uint2*)(esrc16 + (E));                            \
    int sn0 = (int)(sv.x & 0xffffu), sn1 = (int)(sv.x >> 16);            \
    int sn2 = (int)(sv.y & 0xffffu), sn3 = (int)(sv.y >> 16);            \
    const uint4* r0 = x8q + sn0 * 4 + hf * 2;                            \
    const uint4* r1 = x8q + sn1 * 4 + hf * 2;                            \
    const uint4* r2 = x8q + sn2 * 4 + hf * 2;                            \
    const uint4* r3 = x8q + sn3 * 4 + hf * 2;                            \
    uint4 u0a = r0[0], u0b = r0[1];                                      \
    uint4 u1a = r1[0], u1b = r1[1];                                      \
    uint4 u2a = r2[0], u2b = r2[1];                                      \
    uint4 u3a = r3[0], u3b = r3[1];                                      \
    float v0 = el1[sn0 * 8 + h] + er_h;                                  \
    float v1 = el1[sn1 * 8 + h] + er_h;                                  \
    float v2 = el1[sn2 * 8 + h] + er_h;                                  \
    float v3 = el1[sn3 * 8 + h] + er_h;                                  \
    v0 = v0 > 0.f ? v0 : 0.2f * v0;                                      \
    v1 = v1 > 0.f ? v1 : 0.2f * v1;                                      \
    v2 = v2 > 0.f ? v2 : 0.2f * v2;                                      \
    v3 = v3 > 0.f ? v3 : 0.2f * v3;                                      \
    float x0 = __expf(v0), x1 = __expf(v1), x2 = __expf(v2),             \
          x3 = __expf(v3);                                               \
    s += x0 + x1 + x2 + x3;                                              \
    ACC16(u0a, x0, 0); ACC16(u0b, x0, 16);                               \
    ACC16(u1a, x1, 0); ACC16(u1b, x1, 16);                               \
    ACC16(u2a, x2, 0); ACC16(u2b, x2, 16);                               \
    ACC16(u3a, x3, 0); ACC16(u3b, x3, 16);                               \
  }

// ---- D3: layer-1 agg: 16 nodes/block (512 thr), 32 thr/node = head h x
// feat-half hf x edge-parity ep. launch_bounds(512, 4): VGPR cap 128 (2
// blocks/CU = 4 waves/SIMD) -- at the old implicit 64-VGPR cap the compiler
// serialized EDGE4's 12 independent gathers into load-wait-use pairs
// (round-12 PMC: VGPR=64, 87us, VALU 42%, models say ~30us of real work).
// Then per-block MFMA epilogue: h = (xagg/s) @ W1, relu(+b1) . W2 -> feat2. ----
__global__ __launch_bounds__(512, 4) void k_agg1(const int* __restrict__ deg,
    const unsigned short* __restrict__ esrc16, const uint4* __restrict__ x8q,
    const float* __restrict__ el1, const float* __restrict__ er1,
    const ushort16* __restrict__ w1t, const float* __restrict__ b1,
    const float* __restrict__ W2, float* __restrict__ feat2) {
  __shared__ uint4 Ab4[1024];     // 16 KiB: A[8 heads][16 nodes][64 feats] bf16
  __shared__ float redw[8][16];
  int t = threadIdx.x, nl = t >> 5, lt = t & 31;
  int h = lt & 7, hf = (lt >> 3) & 1, ep = lt >> 4;  // head, feat-half, parity
  int n = blockIdx.x * 16 + nl;
  float er_h = er1[n * 8 + h];
  int begin = n * CAP;
  int d = deg[n]; d = d > CAP ? CAP : d;
  float acc[32];
#pragma unroll
  for (int i = 0; i < 32; ++i) acc[i] = 0.f;
  float s = 0.f;
  int G = d >> 2;                  // full 4-edge groups
  for (int g = ep; g < G; g += 2) EDGE4(begin + g * 4);
  if (ep == (G & 1)) {             // tail (<=3 edges) to the "next-turn" lane
    for (int e = begin + G * 4; e < begin + d; ++e) {
      int sN = (int)esrc16[e];
      const uint4* rp = x8q + sN * 4 + hf * 2;
      uint4 ua = rp[0], ub = rp[1];
      float v = el1[sN * 8 + h] + er_h;
      v = v > 0.f ? v : 0.2f * v;
      float ex = __expf(v);
      s += ex;
      ACC16(ua, ex, 0); ACC16(ub, ex, 16);
    }
  }
  // merge the two edge-parity partials (lane ^ 16 = same node/head/half)
  s += __shfl_xor(s, 16, 64);
#pragma unroll
  for (int i = 0; i < 32; ++i) acc[i] += __shfl_xor(acc[i], 16, 64);
  float inv = (d > 0) ? 1.f / s : 0.f;
  // stage scaled xagg to LDS as bf16, XOR-swizzled (key = (row+2h)&7, applied
  // identically on write and read -> bijective within each 128B row).
  // ep==0 lanes only: all c indices compile-time (no runtime reg-array idx).
  if (ep == 0) {
    char* lb = (char*)Ab4 + h * 2048 + nl * 128;
    int swz = ((nl + 2 * h) & 7) << 4;
#pragma unroll
    for (int c = 0; c < 4; ++c) {
      uint4 pk;
      pk.x = (uint32)f2bf(acc[c * 8 + 0] * inv) | ((uint32)f2bf(acc[c * 8 + 1] * inv) << 16);
      pk.y = (uint32)f2bf(acc[c * 8 + 2] * inv) | ((uint32)f2bf(acc[c * 8 + 3] * inv) << 16);
      pk.z = (uint32)f2bf(acc[c * 8 + 4] * inv) | ((uint32)f2bf(acc[c * 8 + 5] * inv) << 16);
      pk.w = (uint32)f2bf(acc[c * 8 + 6] * inv) | ((uint32)f2bf(acc[c * 8 + 7] * inv) << 16);
      *(uint4*)(lb + ((hf * 64 + c * 16) ^ swz)) = pk;
    }
  }
  __syncthreads();
  // ---- MFMA epilogue: 8 waves, wave w handles head w ----
  int w = t >> 6, lane = t & 63, quad = lane >> 4, m = lane & 15;
  float rsum[4] = {0.f, 0.f, 0.f, 0.f};
  const char* ab = (const char*)Ab4 + w * 2048 + m * 128;
  int sw2 = ((m + 2 * w) & 7) << 4;
  bf8v af0 = *(const bf8v*)(ab + ((quad * 16) ^ sw2));
  bf8v af1 = *(const bf8v*)(ab + ((64 + quad * 16) ^ sw2));
#pragma unroll
  for (int ct = 0; ct < 2; ++ct) {
    int colg = w * 32 + ct * 16 + m;
    const bf8v* bw = (const bf8v*)(w1t + colg * 64 + quad * 8);
    bf8v bf0 = bw[0], bf4 = bw[4];
    f32x4 c2 = {0.f, 0.f, 0.f, 0.f};
    c2 = __builtin_amdgcn_mfma_f32_16x16x32_bf16(af0, bf0, c2, 0, 0, 0);
    c2 = __builtin_amdgcn_mfma_f32_16x16x32_bf16(af1, bf4, c2, 0, 0, 0);
    float bb = b1[colg], w2v = W2[colg];
#pragma unroll
    for (int i = 0; i < 4; ++i)
      rsum[i] += fmaxf(c2[i] + bb, 0.f) * w2v;
  }
#pragma unroll
  for (int off = 1; off < 16; off <<= 1) {
#pragma unroll
    for (int i = 0; i < 4; ++i) rsum[i] += __shfl_xor(rsum[i], off, 16);
  }
  if (m == 0) {
#pragma unroll
    for (int i = 0; i < 4; ++i) redw[w][quad * 4 + i] = rsum[i];
  }
  __syncthreads();
  if (t < 16) {
    float r = redw[0][t] + redw[1][t] + redw[2][t] + redw[3][t]
            + redw[4][t] + redw[5][t] + redw[6][t] + redw[7][t];
    feat2[blockIdx.x * 16 + t] = r;
  }
}

// ---- D4: layer-2 fused (el2/er2 on the fly; one gather per edge), sigmoid ----
__global__ __launch_bounds__(256) void k_layer2(const int* __restrict__ deg,
    const unsigned short* __restrict__ esrc16, const float* __restrict__ feat2,
    const float* __restrict__ al2, const float* __restrict__ ar2,
    const float* __restrict__ b2, float* __restrict__ out) {
  int t = threadIdx.x, g = t >> 4, lt = t & 15;
  int n = blockIdx.x * 16 + g;
  int begin = n * CAP;
  int d = deg[n]; d = d > CAP ? CAP : d;
  int end = begin + d;
  float a2 = al2[0];
  float er_n = feat2[n] * ar2[0];
  float num = 0.f, s = 0.f;
  for (int e = begin + lt; e < end; e += 16) {
    int sN = (int)esrc16[e];
    float f = feat2[sN];
    float v = f * a2 + er_n;
    v = v > 0.f ? v : 0.2f * v;
    float ex = __expf(v);
    num += f * ex;
    s += ex;
  }
#pragma unroll
  for (int off = 8; off > 0; off >>= 1) {
    num += __shfl_down(num, off, 16);
    s += __shfl_down(s, off, 16);
  }
  if (lt == 0) {
    float val = (d > 0) ? num / s : 0.f;
    out[n] = 1.f / (1.f + __expf(-(val + b2[0])));
  }
}

extern "C" void kernel_launch(void* const* d_in, const int* in_sizes, int n_in,
                              void* d_out, int out_size, void* d_ws, size_t ws_size,
                              hipStream_t stream) {
  const float* x   = (const float*)d_in[0];
  const int* src   = (const int*)d_in[1];
  const int* dst   = (const int*)d_in[2];
  // d_in[3] = edge_types (unused by reference)
  const float* W1  = (const float*)d_in[4];
  const float* al1 = (const float*)d_in[5];
  const float* ar1 = (const float*)d_in[6];
  const float* b1  = (const float*)d_in[7];
  const float* W2  = (const float*)d_in[8];
  const float* al2 = (const float*)d_in[9];
  const float* ar2 = (const float*)d_in[10];
  const float* b2  = (const float*)d_in[11];

  // Workspace (~13.3 MB), offsets in 4-byte words; 16B-aligned segments.
  float* ws    = (float*)d_ws;
  float* el1   = ws;                       //   400,000 f
  float* er1   = ws + 400000;              //   400,000 f
  float* feat2 = ws + 800000;              //    50,000 f
  int* deg     = (int*)ws + 850000;        //    50,000 i (zeroed in k_init)
  unsigned short* esrc16 = (unsigned short*)((int*)ws + 900000);  // 3.2M u16
  ushort16* w1t = (ushort16*)((int*)ws + 2500000);  // 16,384 bf16 -> 2,508,192
  ushort16* wlr = (ushort16*)((int*)ws + 2508192);  //  1,024 bf16 -> 2,508,704
  uint2* x8w    = (uint2*)((int*)ws + 2508704);     // 3.2M fp8 -> 3,308,704

  k_init<<<117, 256, 0, stream>>>(W1, al1, ar1, w1t, wlr, (int4*)deg);
  k_build_feat<<<BF_GRID, 256, 0, stream>>>(x, wlr, el1, er1, x8w, src, dst,
                                            deg, esrc16);
  k_agg1<<<N_NODES / 16, 512, 0, stream>>>(deg, esrc16, (const uint4*)x8w,
                                           el1, er1, w1t, b1, W2, feat2);
  k_layer2<<<N_NODES / 16, 256, 0, stream>>>(deg, esrc16, feat2, al2, ar2, b2,
                                             (float*)d_out);
}